// Round 8
// baseline (142.886 us; speedup 1.0000x reference)
//
#include <hip/hip_runtime.h>
#include <math.h>

#define U_ 4096
#define T_ 200
#define K_ 64
#define Q_ 10000
#define H_ 128
#define UPB 8    // users (waves) per block in scan
#define PPB 32   // pairs per block in mlp (625 blocks x 32 = 20000)

__device__ __forceinline__ float gelu_f(float x) {
  // exact erf GELU (matches jax.nn.gelu approximate=False)
  return 0.5f * x * (1.0f + erff(x * 0.70710678118654752440f));
}

// ---------------------------------------------------------------------------
// K1 (R8): MLP table -> tab4[2q+rp] = (r, mu, ts, td) + fused kc_of_q.
// LDS-issue diet: lane owns outputs 2j,2j+1 (one b64 W2 read/k instead of
// two b32), k-step-4 with float4 h1 reads (pad 132 keeps 16B alignment).
// ---------------------------------------------------------------------------
__global__ __launch_bounds__(256, 4) void mlp_table_kernel(
    const float* __restrict__ diff_mu, const float* __restrict__ disc_mu,
    const float* __restrict__ W1, const float* __restrict__ b1,
    const float* __restrict__ W2, const float* __restrict__ b2,
    const float* __restrict__ W3, const float* __restrict__ b3,
    const unsigned char* __restrict__ kmap,
    float4* __restrict__ tab4, int* __restrict__ kc_of_q) {
  __shared__ __align__(16) float W2s[64 * H_];        // 32 KB: one half of W2
  __shared__ __align__(16) float h1buf[PPB][H_ + 4];  // pad->132 (16B-aligned rows)

  const int tid = threadIdx.x;
  const int lane = tid & 63, w = tid >> 6;
  const int base = blockIdx.x * PPB;

  // fused kc_of_q: first 40 blocks cover Q=10000
  if (blockIdx.x < 40) {
    int q = blockIdx.x * 256 + tid;
    if (q < Q_) {
      const unsigned char* km = kmap + (size_t)q * K_;
      int kc = 0;
#pragma unroll
      for (int k = 0; k < K_; ++k)
        if (km[k]) kc = k;  // one-hot
      kc_of_q[q] = kc;
    }
  }

  // layer 1: 32 pairs x 128 hidden
  for (int v = tid; v < PPB * H_; v += 256) {
    int pl = v >> 7, j = v & 127;
    int pg = base + pl, q = pg >> 1;
    float rf = (float)(pg & 1);
    float a = fmaf(diff_mu[q], W1[j], b1[j]);
    a = fmaf(disc_mu[q], W1[H_ + j], a);
    a = fmaf(rf, W1[2 * H_ + j], a);
    h1buf[pl][j] = gelu_f(a);
  }
  // stage W2 rows 0..63 (float4 coalesced)
  for (int v = tid; v < 2048; v += 256)
    ((float4*)W2s)[v] = ((const float4*)W2)[v];
  __syncthreads();

  // layer 2: wave w owns pairs w*8..w*8+7; lane j -> outputs 2j, 2j+1
  float a0[8], a1[8];
#pragma unroll
  for (int p = 0; p < 8; ++p) { a0[p] = 0.f; a1[p] = 0.f; }

#pragma clang loop unroll_count(2)
  for (int kq = 0; kq < 64; kq += 4) {
    float2 wv[4];
#pragma unroll
    for (int kk = 0; kk < 4; ++kk)
      wv[kk] = *(const float2*)&W2s[(kq + kk) * H_ + 2 * lane];  // b64
#pragma unroll
    for (int p = 0; p < 8; ++p) {
      float4 hv = *(const float4*)&h1buf[w * 8 + p][kq];         // b128
      a0[p] = fmaf(wv[0].x, hv.x, a0[p]); a1[p] = fmaf(wv[0].y, hv.x, a1[p]);
      a0[p] = fmaf(wv[1].x, hv.y, a0[p]); a1[p] = fmaf(wv[1].y, hv.y, a1[p]);
      a0[p] = fmaf(wv[2].x, hv.z, a0[p]); a1[p] = fmaf(wv[2].y, hv.z, a1[p]);
      a0[p] = fmaf(wv[3].x, hv.w, a0[p]); a1[p] = fmaf(wv[3].y, hv.w, a1[p]);
    }
  }
  __syncthreads();
  // stage W2 rows 64..127
  for (int v = tid; v < 2048; v += 256)
    ((float4*)W2s)[v] = ((const float4*)W2)[2048 + v];
  __syncthreads();
#pragma clang loop unroll_count(2)
  for (int kq = 0; kq < 64; kq += 4) {
    float2 wv[4];
#pragma unroll
    for (int kk = 0; kk < 4; ++kk)
      wv[kk] = *(const float2*)&W2s[(kq + kk) * H_ + 2 * lane];
#pragma unroll
    for (int p = 0; p < 8; ++p) {
      float4 hv = *(const float4*)&h1buf[w * 8 + p][64 + kq];
      a0[p] = fmaf(wv[0].x, hv.x, a0[p]); a1[p] = fmaf(wv[0].y, hv.x, a1[p]);
      a0[p] = fmaf(wv[1].x, hv.y, a0[p]); a1[p] = fmaf(wv[1].y, hv.y, a1[p]);
      a0[p] = fmaf(wv[2].x, hv.z, a0[p]); a1[p] = fmaf(wv[2].y, hv.z, a1[p]);
      a0[p] = fmaf(wv[3].x, hv.w, a0[p]); a1[p] = fmaf(wv[3].y, hv.w, a1[p]);
    }
  }

  // layer 3 + head math: lane j holds h2[2j], h2[2j+1]
  float2 b2v = *(const float2*)&b2[2 * lane];
  float4 w3v = *(const float4*)&W3[4 * lane];  // W3[2j][0..1], W3[2j+1][0..1]
  float b30 = b3[0], b31 = b3[1];
#pragma unroll
  for (int p = 0; p < 8; ++p) {
    float h2a = gelu_f(a0[p] + b2v.x);
    float h2b = gelu_f(a1[p] + b2v.y);
    float s0 = h2a * w3v.x + h2b * w3v.z;
    float s1 = h2a * w3v.y + h2b * w3v.w;
#pragma unroll
    for (int off = 32; off > 0; off >>= 1) {
      s0 += __shfl_xor(s0, off, 64);
      s1 += __shfl_xor(s1, off, 64);
    }
    if (lane == 0) {
      float mu = gelu_f(s0 + b30);
      float lv = gelu_f(s1 + b31);
      float sd = fmaxf(expf(0.5f * lv), 1e-8f);
      int pg = base + w * 8 + p;
      int q = pg >> 1;
      tab4[pg] = make_float4(1.0f / (sd * sd), mu, disc_mu[q], diff_mu[q]);
    }
  }
}

// ---------------------------------------------------------------------------
// K2 (R8): barrier-free scan, LDS-op diet + stash-free forward.
// Per-step data packed as float4 (b,c,ts,td) in a wave-private LDS column;
// forward loop: 1 uniform b128 + 1 byte read, ZERO LDS writes (the ability
// stash ds_write — present in R5/R6/R7 — serialized every step at DS
// round-trip latency; logits now go straight to global from the hit lane).
// ---------------------------------------------------------------------------
__global__ __launch_bounds__(512) void scan_kernel(
    const int* __restrict__ q_id, const int* __restrict__ resp,
    const float4* __restrict__ tab4, const int* __restrict__ kc_of_q,
    float* __restrict__ out) {
  __shared__ __align__(16) float4 q4s[T_ * (UPB + 1)];  // [t][u] (b|r, c|mu, ts, td)
  __shared__ unsigned char kcs[T_ * UPB];               // [t][u]

  const int tid = threadIdx.x;
  const int lane = tid & 63;
  const int ul = tid >> 6;
  const int gu = blockIdx.x * UPB + ul;

  // ---- P0: gather (coalesced q/resp; tab4+kc L2/L3-resident) ----
  const int* qrow = q_id + (size_t)gu * T_;
  const int* rrow = resp + (size_t)gu * T_;
#pragma unroll
  for (int i = 0; i < 4; ++i) {
    int t = i * 64 + lane;
    if (t < T_) {
      int q = qrow[t];
      int rp = rrow[t];
      q4s[t * (UPB + 1) + ul] = tab4[q * 2 + rp];  // (r, mu, ts, td)
      kcs[t * UPB + ul] = (unsigned char)kc_of_q[q];
    }
  }

  // ---- P1: backward per wave (own user), uniform b64 reads of (r,mu) ----
  // b = 1/(2 + r - b_next); c = b*(c_next + r*mu)  (passing math since R3)
  float tb[4], tcc[4];
  float b = 1.0f, c = 0.0f;
#pragma unroll 8
  for (int s = 7; s >= 0; --s) {  // tile 3: t = 199..192
    int t = 192 + s;
    float2 rm = *(const float2*)&q4s[t * (UPB + 1) + ul];
    float x_ = 2.0f + rm.x - b;
    float ib = __builtin_amdgcn_rcpf(x_);
    ib = ib * (2.0f - x_ * ib);  // Newton step
    b = ib;
    c = b * fmaf(rm.x, rm.y, c);
    bool cap = (lane == s);
    tb[3] = cap ? b : tb[3];
    tcc[3] = cap ? c : tcc[3];
  }
#pragma unroll
  for (int i = 2; i >= 0; --i) {
#pragma unroll 8
    for (int s = 63; s >= 0; --s) {
      int t = i * 64 + s;
      float2 rm = *(const float2*)&q4s[t * (UPB + 1) + ul];
      float x_ = 2.0f + rm.x - b;
      float ib = __builtin_amdgcn_rcpf(x_);
      ib = ib * (2.0f - x_ * ib);
      b = ib;
      c = b * fmaf(rm.x, rm.y, c);
      bool cap = (lane == s);
      tb[i] = cap ? b : tb[i];
      tcc[i] = cap ? c : tcc[i];
    }
  }
  // bulk writeback of (b,c) into .xy (in-order after all chain reads)
#pragma unroll
  for (int i = 0; i < 4; ++i) {
    int t = i * 64 + lane;
    if (t < T_)
      *(float2*)&q4s[t * (UPB + 1) + ul] = make_float2(tb[i], tcc[i]);
  }

  // ---- P2: forward, lane = KC; no LDS writes; direct logit store ----
  float x = 0.0f;
  float* logits = out + (size_t)gu * T_;
  float* last = out + (size_t)U_ * T_;
#pragma unroll 8
  for (int t = 0; t < T_; ++t) {
    float4 g = q4s[t * (UPB + 1) + ul];  // uniform b128: (b, c, ts, td)
    int kc = (int)kcs[t * UPB + ul];     // uniform byte
    float xn = fmaf(g.x, x, g.y);
    bool hit = (lane == kc);
    x = hit ? xn : x;
    if (hit) logits[t] = g.z * (xn - g.w);  // fire-and-forget global store
  }
  last[(size_t)gu * K_ + lane] = x;  // last_ability_kc straight from registers
}

// ---------------------------------------------------------------------------
extern "C" void kernel_launch(void* const* d_in, const int* in_sizes, int n_in,
                              void* d_out, int out_size, void* d_ws,
                              size_t ws_size, hipStream_t stream) {
  // setup_inputs order:
  // 0 mask 1 q_id(i32,U*T) 2 kmap(bool,Q*K) 3 resp(i32) 4 diff_mu 5 disc_mu
  // 6 W1 7 b1 8 W2 9 b2 10 W3 11 b3
  const int* q_id = (const int*)d_in[1];
  const unsigned char* kmap = (const unsigned char*)d_in[2];
  const int* resp = (const int*)d_in[3];
  const float* diff_mu = (const float*)d_in[4];
  const float* disc_mu = (const float*)d_in[5];
  const float* W1 = (const float*)d_in[6];
  const float* b1 = (const float*)d_in[7];
  const float* W2 = (const float*)d_in[8];
  const float* b2 = (const float*)d_in[9];
  const float* W3 = (const float*)d_in[10];
  const float* b3 = (const float*)d_in[11];
  float* out = (float*)d_out;
  char* ws = (char*)d_ws;

  auto align512 = [](size_t x) { return (x + 511) & ~(size_t)511; };
  size_t o = 0;
  float4* tab4 = (float4*)(ws + o);  o = align512(o + (size_t)2 * Q_ * 16);
  int* kc_of_q = (int*)(ws + o);     o = align512(o + (size_t)Q_ * 4);
  (void)ws_size; (void)in_sizes; (void)n_in; (void)out_size;

  mlp_table_kernel<<<Q_ * 2 / PPB, 256, 0, stream>>>(
      diff_mu, disc_mu, W1, b1, W2, b2, W3, b3, kmap, tab4, kc_of_q);
  scan_kernel<<<U_ / UPB, 512, 0, stream>>>(q_id, resp, tab4, kc_of_q, out);
}

// Round 10
// 142.780 us; speedup vs baseline: 1.0007x; 1.0007x over previous
//
#include <hip/hip_runtime.h>
#include <math.h>

#define U_ 4096
#define T_ 200
#define K_ 64
#define Q_ 10000
#define H_ 128
#define UPB 8    // users (waves) per block in scan
#define PPB 32   // pairs per block in mlp (625 blocks x 32 = 20000)

__device__ __forceinline__ float gelu_f(float x) {
  // exact erf GELU (matches jax.nn.gelu approximate=False)
  return 0.5f * x * (1.0f + erff(x * 0.70710678118654752440f));
}

// ---------------------------------------------------------------------------
// K1 (R10): MLP table -> tab4[2q+rp] = (2+r, r*mu, ts|kc, td).
// kc via per-wave ballot (lane k reads kmap[q*64+k] coalesced; one-hot row
// -> ballot bit -> ctz, GUARDED against m==0 poison — R9's suspected NaN).
// kc packed into low 6 mantissa bits of ts (rel err <= 2^-17; margin 0.03).
// ---------------------------------------------------------------------------
__global__ __launch_bounds__(256, 4) void mlp_table_kernel(
    const float* __restrict__ diff_mu, const float* __restrict__ disc_mu,
    const float* __restrict__ W1, const float* __restrict__ b1,
    const float* __restrict__ W2, const float* __restrict__ b2,
    const float* __restrict__ W3, const float* __restrict__ b3,
    const unsigned char* __restrict__ kmap,
    float4* __restrict__ tab4) {
  __shared__ __align__(16) float W2s[64 * H_];        // 32 KB: one half of W2
  __shared__ __align__(16) float h1buf[PPB][H_ + 4];  // pad->132 (16B rows)

  const int tid = threadIdx.x;
  const int lane = tid & 63, w = tid >> 6;
  const int base = blockIdx.x * PPB;

  // per-wave ballot kc for this wave's 4 questions (q0..q0+3)
  const int q0 = blockIdx.x * 16 + w * 4;
  int kcw[4];
#pragma unroll
  for (int qi = 0; qi < 4; ++qi) {
    unsigned char kb = kmap[(size_t)(q0 + qi) * K_ + lane];  // coalesced 64B
    unsigned long long m = __ballot(kb != 0);                // one-hot row
    kcw[qi] = (m != 0ull) ? (int)__builtin_ctzll(m) : 0;     // guarded: no poison
  }

  // layer 1: 32 pairs x 128 hidden
  for (int v = tid; v < PPB * H_; v += 256) {
    int pl = v >> 7, j = v & 127;
    int pg = base + pl, q = pg >> 1;
    float rf = (float)(pg & 1);
    float a = fmaf(diff_mu[q], W1[j], b1[j]);
    a = fmaf(disc_mu[q], W1[H_ + j], a);
    a = fmaf(rf, W1[2 * H_ + j], a);
    h1buf[pl][j] = gelu_f(a);
  }
  // stage W2 rows 0..63 (float4 coalesced)
  for (int v = tid; v < 2048; v += 256)
    ((float4*)W2s)[v] = ((const float4*)W2)[v];
  __syncthreads();

  // layer 2: wave w owns pairs w*8..w*8+7; lane j -> outputs 2j, 2j+1
  float a0[8], a1[8];
#pragma unroll
  for (int p = 0; p < 8; ++p) { a0[p] = 0.f; a1[p] = 0.f; }

#pragma clang loop unroll_count(2)
  for (int kq = 0; kq < 64; kq += 4) {
    float2 wv[4];
#pragma unroll
    for (int kk = 0; kk < 4; ++kk)
      wv[kk] = *(const float2*)&W2s[(kq + kk) * H_ + 2 * lane];  // b64
#pragma unroll
    for (int p = 0; p < 8; ++p) {
      float4 hv = *(const float4*)&h1buf[w * 8 + p][kq];         // b128
      a0[p] = fmaf(wv[0].x, hv.x, a0[p]); a1[p] = fmaf(wv[0].y, hv.x, a1[p]);
      a0[p] = fmaf(wv[1].x, hv.y, a0[p]); a1[p] = fmaf(wv[1].y, hv.y, a1[p]);
      a0[p] = fmaf(wv[2].x, hv.z, a0[p]); a1[p] = fmaf(wv[2].y, hv.z, a1[p]);
      a0[p] = fmaf(wv[3].x, hv.w, a0[p]); a1[p] = fmaf(wv[3].y, hv.w, a1[p]);
    }
  }
  __syncthreads();
  // stage W2 rows 64..127
  for (int v = tid; v < 2048; v += 256)
    ((float4*)W2s)[v] = ((const float4*)W2)[2048 + v];
  __syncthreads();
#pragma clang loop unroll_count(2)
  for (int kq = 0; kq < 64; kq += 4) {
    float2 wv[4];
#pragma unroll
    for (int kk = 0; kk < 4; ++kk)
      wv[kk] = *(const float2*)&W2s[(kq + kk) * H_ + 2 * lane];
#pragma unroll
    for (int p = 0; p < 8; ++p) {
      float4 hv = *(const float4*)&h1buf[w * 8 + p][64 + kq];
      a0[p] = fmaf(wv[0].x, hv.x, a0[p]); a1[p] = fmaf(wv[0].y, hv.x, a1[p]);
      a0[p] = fmaf(wv[1].x, hv.y, a0[p]); a1[p] = fmaf(wv[1].y, hv.y, a1[p]);
      a0[p] = fmaf(wv[2].x, hv.z, a0[p]); a1[p] = fmaf(wv[2].y, hv.z, a1[p]);
      a0[p] = fmaf(wv[3].x, hv.w, a0[p]); a1[p] = fmaf(wv[3].y, hv.w, a1[p]);
    }
  }

  // layer 3 + head: lane j holds h2[2j], h2[2j+1]
  float2 b2v = *(const float2*)&b2[2 * lane];
  float4 w3v = *(const float4*)&W3[4 * lane];
  float b30 = b3[0], b31 = b3[1];
#pragma unroll
  for (int p = 0; p < 8; ++p) {
    float h2a = gelu_f(a0[p] + b2v.x);
    float h2b = gelu_f(a1[p] + b2v.y);
    float s0 = h2a * w3v.x + h2b * w3v.z;
    float s1 = h2a * w3v.y + h2b * w3v.w;
#pragma unroll
    for (int off = 32; off > 0; off >>= 1) {
      s0 += __shfl_xor(s0, off, 64);
      s1 += __shfl_xor(s1, off, 64);
    }
    if (lane == 0) {
      float mu = gelu_f(s0 + b30);
      float lv = gelu_f(s1 + b31);
      float sd = fmaxf(expf(0.5f * lv), 1e-8f);
      float r = 1.0f / (sd * sd);
      int pg = base + w * 8 + p;
      int q = pg >> 1;
      int tsb = (__float_as_int(disc_mu[q]) & ~63) | (kcw[p >> 1] & 63);
      tab4[pg] = make_float4(2.0f + r, r * mu, __int_as_float(tsb),
                             diff_mu[q]);
    }
  }
}

// ---------------------------------------------------------------------------
// K2 (R10): barrier-free scan, row layout. vs R9: the forward stash is an
// exec-masked predicated LDS store (R5-R7's proven pattern) instead of the
// address-select flat store; tb/tcc zero-initialized (no undef selects).
// Backward: uniform b64 reads of (2+r, r*mu), cndmask capture, bulk (b,c)
// writeback into .xy. Forward: ONE uniform b128 read/step, kc from the ts
// mantissa, hit lane stashes the logit into .y.
// ---------------------------------------------------------------------------
__global__ __launch_bounds__(512) void scan_kernel(
    const int* __restrict__ q_id, const int* __restrict__ resp,
    const float4* __restrict__ tab4, float* __restrict__ out) {
  __shared__ __align__(16) float4 q4s[UPB][T_];  // 25.6 KB, wave-private rows

  const int tid = threadIdx.x;
  const int lane = tid & 63;
  const int ul = tid >> 6;
  const int gu = blockIdx.x * UPB + ul;

  // ---- P0: gather (coalesced q/resp; tab4 L2-resident 320 KB) ----
  const int* qrow = q_id + (size_t)gu * T_;
  const int* rrow = resp + (size_t)gu * T_;
#pragma unroll
  for (int i = 0; i < 4; ++i) {
    int t = i * 64 + lane;
    if (t < T_) {
      int q = qrow[t];
      int rp = rrow[t];
      q4s[ul][t] = tab4[q * 2 + rp];  // (2+r, r*mu, ts|kc, td), b128 contig
    }
  }

  // ---- P1: backward per wave; b = 1/((2+r) - b_next); c = b*(rmu + c) ----
  float tb[4] = {0.f, 0.f, 0.f, 0.f}, tcc[4] = {0.f, 0.f, 0.f, 0.f};
  float b = 1.0f, c = 0.0f;
#pragma unroll 8
  for (int s = 7; s >= 0; --s) {  // tile 3: t = 199..192
    float2 rm = *(const float2*)&q4s[ul][192 + s];
    float x_ = rm.x - b;
    float ib = __builtin_amdgcn_rcpf(x_);
    ib = ib * (2.0f - x_ * ib);  // one Newton step (passing math since R3)
    b = ib;
    c = b * (rm.y + c);
    bool cap = (lane == s);
    tb[3] = cap ? b : tb[3];
    tcc[3] = cap ? c : tcc[3];
  }
#pragma unroll
  for (int i = 2; i >= 0; --i) {
#pragma unroll 8
    for (int s = 63; s >= 0; --s) {
      float2 rm = *(const float2*)&q4s[ul][i * 64 + s];
      float x_ = rm.x - b;
      float ib = __builtin_amdgcn_rcpf(x_);
      ib = ib * (2.0f - x_ * ib);
      b = ib;
      c = b * (rm.y + c);
      bool cap = (lane == s);
      tb[i] = cap ? b : tb[i];
      tcc[i] = cap ? c : tcc[i];
    }
  }
  // bulk writeback of (b,c) into .xy (all chain reads precede these writes)
#pragma unroll
  for (int i = 0; i < 4; ++i) {
    int t = i * 64 + lane;
    if (t < T_) *(float2*)&q4s[ul][t] = make_float2(tb[i], tcc[i]);
  }

  // ---- P2: forward, lane = KC; one b128/step; predicated logit stash ----
  float x = 0.0f;
  float* rowf = (float*)&q4s[ul][0];  // row base as float*; .y of elem t at 4t+1
#pragma unroll 8
  for (int t = 0; t < T_; ++t) {
    float4 g = q4s[ul][t];            // uniform b128 broadcast
    int kc = __float_as_int(g.z) & 63;
    float xn = fmaf(g.x, x, g.y);
    bool hit = (lane == kc);
    x = hit ? xn : x;
    if (hit) rowf[t * 4 + 1] = g.z * (xn - g.w);  // exec-masked ds_write_b32
  }

  // ---- P3: epilogue ----
  float* logits = out + (size_t)gu * T_;
  float* last = out + (size_t)U_ * T_;
#pragma unroll
  for (int i = 0; i < 4; ++i) {
    int t = i * 64 + lane;
    if (t < T_) logits[t] = q4s[ul][t].y;  // coalesced store
  }
  last[(size_t)gu * K_ + lane] = x;  // last_ability_kc straight from registers
}

// ---------------------------------------------------------------------------
extern "C" void kernel_launch(void* const* d_in, const int* in_sizes, int n_in,
                              void* d_out, int out_size, void* d_ws,
                              size_t ws_size, hipStream_t stream) {
  // setup_inputs order:
  // 0 mask 1 q_id(i32,U*T) 2 kmap(bool,Q*K) 3 resp(i32) 4 diff_mu 5 disc_mu
  // 6 W1 7 b1 8 W2 9 b2 10 W3 11 b3
  const int* q_id = (const int*)d_in[1];
  const unsigned char* kmap = (const unsigned char*)d_in[2];
  const int* resp = (const int*)d_in[3];
  const float* diff_mu = (const float*)d_in[4];
  const float* disc_mu = (const float*)d_in[5];
  const float* W1 = (const float*)d_in[6];
  const float* b1 = (const float*)d_in[7];
  const float* W2 = (const float*)d_in[8];
  const float* b2 = (const float*)d_in[9];
  const float* W3 = (const float*)d_in[10];
  const float* b3 = (const float*)d_in[11];
  float* out = (float*)d_out;
  char* ws = (char*)d_ws;

  float4* tab4 = (float4*)ws;  // 320 KB
  (void)ws_size; (void)in_sizes; (void)n_in; (void)out_size;

  mlp_table_kernel<<<Q_ * 2 / PPB, 256, 0, stream>>>(
      diff_mu, disc_mu, W1, b1, W2, b2, W3, b3, kmap, tab4);
  scan_kernel<<<U_ / UPB, 512, 0, stream>>>(q_id, resp, tab4, out);
}